// Round 19
// baseline (73.202 us; speedup 1.0000x reference)
//
#include <hip/hip_runtime.h>
#include <hip/hip_bf16.h>
#include <cstdint>
#include <cstddef>

// Problem constants
#define Bsz 16384
#define Esz 16
#define Ssz 64
#define Asz 32
#define Isz 96   // S + A
#define HSz 64
#define HRz 32

#define NTM 256       // 4 waves
#define NSB 512       // state blocks
#define SCHUNK 512    // rows per state block
#define SNTILE 8      // tiles of 64 rows
#define NRB 128       // reward blocks
#define RCHUNK 2048
#define RNTILE 32

typedef __attribute__((ext_vector_type(8))) short bf16x8;
typedef __attribute__((ext_vector_type(4))) short short4v;
typedef __attribute__((ext_vector_type(4))) float f32x4;

static __device__ __forceinline__ short f2bf(float f) {
    __hip_bfloat16 b = __float2bfloat16(f);   // pairs into v_cvt_pk_bf16_f32
    return *reinterpret_cast<short*>(&b);
}
static __device__ __forceinline__ float bf2f(short s) {
    union { uint32_t u; float f; } v; v.u = ((uint32_t)(uint16_t)s) << 16; return v.f;
}
static __device__ __forceinline__ bf16x8 pack8(float4 lo, float4 hi) {
    bf16x8 r;
    r[0] = f2bf(lo.x); r[1] = f2bf(lo.y); r[2] = f2bf(lo.z); r[3] = f2bf(lo.w);
    r[4] = f2bf(hi.x); r[5] = f2bf(hi.y); r[6] = f2bf(hi.z); r[7] = f2bf(hi.w);
    return r;
}

// COLUMN-SPLIT design: each wave owns output-column slice nt = w.
// Weight cost per wave: 3 W1 frags + 2 W2 frags = 20 VGPRs (vs 104 in R16).
// All per-tile temporaries die inside `unroll 1` loops -> naturally ~100-120
// VGPR -> 4 waves/SIMD WITHOUT coercion (no min-waves launch bound).
// Blocks [0,NSB): state (2 barriers/tile, HT/OT through LDS, full-line
// nt-stores, XCD sibling swizzle). Blocks [NSB,NSB+NRB): reward (light).
__global__ __launch_bounds__(NTM)
void fused_all(const float* __restrict__ state, const float* __restrict__ action,
               const float* __restrict__ W1, const float* __restrict__ b1,
               const float* __restrict__ W2, const float* __restrict__ b2,
               const float* __restrict__ rW1, const float* __restrict__ rb1,
               const float* __restrict__ rW2, const float* __restrict__ rb2,
               float* __restrict__ outS, float* __restrict__ outR)
{
    __shared__ __align__(16) short HT[64][68];   //  8704 B  block H (row, stride 68 shorts)
    __shared__ __align__(16) float OT[64][72];   // 18432 B  block output staging
    // total 27136 B

    const int bid = blockIdx.x;
    const int tid = threadIdx.x;
    const int w = tid >> 6, lane = tid & 63;
    const int lr = lane & 15, lg = lane >> 4;

    if (bid < NSB) {
        // ================= STATE PATH =================
        // XCD sibling swizzle (bijective over 512): 16 e-siblings share an XCD
        const int xcd = bid & 7;
        const int rem = bid >> 3;
        const int e   = rem & (Esz - 1);
        const int c0  = (xcd + 8 * (rem >> 4)) * SCHUNK;

        // Wave-owned weight fragments (nt = w): lane holds
        // W[k = kk*32 + lg*8 + t][n = w*16 + lr], t=0..7.
        bf16x8 w1r[3], w2r[2];
        {
            const float* base = W1 + (size_t)e * Isz * HSz;
            #pragma unroll
            for (int kk = 0; kk < 3; ++kk) {
                const float* p = base + (kk * 32 + lg * 8) * HSz + w * 16 + lr;
                bf16x8 r;
                #pragma unroll
                for (int t = 0; t < 8; ++t) r[t] = f2bf(p[t * HSz]);
                w1r[kk] = r;
            }
        }
        {
            const float* base = W2 + (size_t)e * HSz * Ssz;
            #pragma unroll
            for (int kk = 0; kk < 2; ++kk) {
                const float* p = base + (kk * 32 + lg * 8) * Ssz + w * 16 + lr;
                bf16x8 r;
                #pragma unroll
                for (int t = 0; t < 8; ++t) r[t] = f2bf(p[t * Ssz]);
                w2r[kk] = r;
            }
        }
        // Wave-slice biases packed bf16 (D slots: n = w*16 + lg*4 + j)
        short4v b1p, b2p;
        {
            float4 v1 = *(const float4*)&b1[e * HSz + w * 16 + lg * 4];
            float4 v2 = *(const float4*)&b2[e * Ssz + w * 16 + lg * 4];
            b1p = (short4v){ f2bf(v1.x), f2bf(v1.y), f2bf(v1.z), f2bf(v1.w) };
            b2p = (short4v){ f2bf(v2.x), f2bf(v2.y), f2bf(v2.z), f2bf(v2.w) };
        }

        #pragma unroll 1
        for (int t = 0; t < SNTILE; ++t) {
            const int rbase = c0 + t * 64;

            // ---- L1 phase: 4 m-tiles, all transients die per iteration ----
            #pragma unroll 1
            for (int mt = 0; mt < 4; ++mt) {
                const int row = rbase + mt * 16 + lr;
                const float* sp = state  + (size_t)row * Ssz + lg * 8;
                const float* ap = action + (size_t)row * Asz + lg * 8;
                bf16x8 a0 = pack8(*(const float4*)(sp),      *(const float4*)(sp + 4));
                bf16x8 a1 = pack8(*(const float4*)(sp + 32), *(const float4*)(sp + 36));
                bf16x8 a2 = pack8(*(const float4*)(ap),      *(const float4*)(ap + 4));
                f32x4 acc = (f32x4){ bf2f(b1p[0]), bf2f(b1p[1]), bf2f(b1p[2]), bf2f(b1p[3]) };
                acc = __builtin_amdgcn_mfma_f32_16x16x32_bf16(w1r[0], a0, acc, 0, 0, 0);
                acc = __builtin_amdgcn_mfma_f32_16x16x32_bf16(w1r[1], a1, acc, 0, 0, 0);
                acc = __builtin_amdgcn_mfma_f32_16x16x32_bf16(w1r[2], a2, acc, 0, 0, 0);
                short4v p = { f2bf(fmaxf(acc[0], 0.f)), f2bf(fmaxf(acc[1], 0.f)),
                              f2bf(fmaxf(acc[2], 0.f)), f2bf(fmaxf(acc[3], 0.f)) };
                *(short4v*)&HT[mt * 16 + lr][w * 16 + lg * 4] = p;
            }
            __syncthreads();   // HT complete

            // ---- L2 phase ----
            #pragma unroll 1
            for (int mt = 0; mt < 4; ++mt) {
                bf16x8 h0 = *(const bf16x8*)&HT[mt * 16 + lr][lg * 8];
                bf16x8 h1 = *(const bf16x8*)&HT[mt * 16 + lr][32 + lg * 8];
                f32x4 acc = (f32x4){ bf2f(b2p[0]), bf2f(b2p[1]), bf2f(b2p[2]), bf2f(b2p[3]) };
                acc = __builtin_amdgcn_mfma_f32_16x16x32_bf16(w2r[0], h0, acc, 0, 0, 0);
                acc = __builtin_amdgcn_mfma_f32_16x16x32_bf16(w2r[1], h1, acc, 0, 0, 0);
                *(f32x4*)&OT[mt * 16 + lr][w * 16 + lg * 4] = acc;
            }
            __syncthreads();   // OT complete

            // ---- Store phase: block's 16 KB region, fully contiguous nt-stores ----
            {
                const size_t obase = ((size_t)e * Bsz + rbase) * Ssz;
                #pragma unroll
                for (int q = 0; q < 4; ++q) {
                    const int f = q * 1024 + tid * 4;
                    f32x4 v = *(const f32x4*)&OT[f >> 6][f & 63];
                    __builtin_nontemporal_store(v, (f32x4*)&outS[obase + f]);
                }
            }
        }
    } else {
        // ================= REWARD PATH (light, no barriers) =================
        const int rbid = bid - NSB;
        const int e  = rbid & (Esz - 1);
        const int c0 = (rbid >> 4) * RCHUNK;

        bf16x8 rw1r[2][3];
        {
            const float* base = rW1 + (size_t)e * Isz * HRz;
            #pragma unroll
            for (int nt = 0; nt < 2; ++nt)
                #pragma unroll
                for (int kk = 0; kk < 3; ++kk) {
                    const float* p = base + (kk * 32 + lg * 8) * HRz + nt * 16 + lr;
                    bf16x8 r;
                    #pragma unroll
                    for (int t = 0; t < 8; ++t) r[t] = f2bf(p[t * HRz]);
                    rw1r[nt][kk] = r;
                }
        }
        short4v rb1p[2], rw2p[2];
        #pragma unroll
        for (int nt = 0; nt < 2; ++nt) {
            float4 v1 = *(const float4*)&rb1[e * HRz + nt * 16 + lg * 4];
            float4 v2 = *(const float4*)&rW2[e * HRz + nt * 16 + lg * 4];
            rb1p[nt] = (short4v){ f2bf(v1.x), f2bf(v1.y), f2bf(v1.z), f2bf(v1.w) };
            rw2p[nt] = (short4v){ f2bf(v2.x), f2bf(v2.y), f2bf(v2.z), f2bf(v2.w) };
        }
        const float rb2s = rb2[e];

        #pragma unroll 1
        for (int t = 0; t < RNTILE; ++t) {
            const int row = c0 + t * 64 + w * 16 + lr;
            const float* sp = state  + (size_t)row * Ssz + lg * 8;
            const float* ap = action + (size_t)row * Asz + lg * 8;
            bf16x8 a0 = pack8(*(const float4*)(sp),      *(const float4*)(sp + 4));
            bf16x8 a1 = pack8(*(const float4*)(sp + 32), *(const float4*)(sp + 36));
            bf16x8 a2 = pack8(*(const float4*)(ap),      *(const float4*)(ap + 4));

            float rp = 0.f;
            #pragma unroll
            for (int nt = 0; nt < 2; ++nt) {
                f32x4 acc = (f32x4){ bf2f(rb1p[nt][0]), bf2f(rb1p[nt][1]),
                                     bf2f(rb1p[nt][2]), bf2f(rb1p[nt][3]) };
                acc = __builtin_amdgcn_mfma_f32_16x16x32_bf16(rw1r[nt][0], a0, acc, 0, 0, 0);
                acc = __builtin_amdgcn_mfma_f32_16x16x32_bf16(rw1r[nt][1], a1, acc, 0, 0, 0);
                acc = __builtin_amdgcn_mfma_f32_16x16x32_bf16(rw1r[nt][2], a2, acc, 0, 0, 0);
                rp += fmaxf(acc[0], 0.f) * bf2f(rw2p[nt][0]);
                rp += fmaxf(acc[1], 0.f) * bf2f(rw2p[nt][1]);
                rp += fmaxf(acc[2], 0.f) * bf2f(rw2p[nt][2]);
                rp += fmaxf(acc[3], 0.f) * bf2f(rw2p[nt][3]);
            }
            rp += __shfl_xor(rp, 16);
            rp += __shfl_xor(rp, 32);
            if (lane < 16)
                __builtin_nontemporal_store(fminf(fmaxf(rp + rb2s, -100.f), 200.f),
                                            &outR[(size_t)e * Bsz + row]);
        }
    }
}

extern "C" void kernel_launch(void* const* d_in, const int* in_sizes, int n_in,
                              void* d_out, int out_size, void* d_ws, size_t ws_size,
                              hipStream_t stream) {
    const float* state  = (const float*)d_in[0];
    const float* action = (const float*)d_in[1];
    const float* W1  = (const float*)d_in[2];
    const float* b1  = (const float*)d_in[3];
    const float* W2  = (const float*)d_in[4];
    const float* b2  = (const float*)d_in[5];
    const float* rW1 = (const float*)d_in[6];
    const float* rb1 = (const float*)d_in[7];
    const float* rW2 = (const float*)d_in[8];
    const float* rb2 = (const float*)d_in[9];

    float* outS = (float*)d_out;                      // [E, B, S]
    float* outR = outS + (size_t)Esz * Bsz * Ssz;     // [E, B, 1]

    fused_all<<<NSB + NRB, NTM, 0, stream>>>(         // 640 blocks, 1 generation
        state, action, W1, b1, W2, b2, rW1, rb1, rW2, rb2, outS, outR);
}

// Round 20
// 30.145 us; speedup vs baseline: 2.4283x; 2.4283x over previous
//
#include <hip/hip_runtime.h>
#include <hip/hip_bf16.h>
#include <cstdint>
#include <cstddef>

// Problem constants
#define Bsz 16384
#define Esz 16
#define Ssz 64
#define Asz 32
#define Isz 96   // S + A
#define HSz 64
#define HRz 32

#define NTM 256       // 4 waves
#define CHUNK 256     // batch rows per block (2-generation grid)
#define NTILE 4       // CHUNK / (4 waves * 16 rows)

typedef __attribute__((ext_vector_type(8))) short bf16x8;
typedef __attribute__((ext_vector_type(4))) short short4v;
typedef __attribute__((ext_vector_type(4))) float f32x4;

static __device__ __forceinline__ short f2bf(float f) {
    __hip_bfloat16 b = __float2bfloat16(f);   // pairs into v_cvt_pk_bf16_f32
    return *reinterpret_cast<short*>(&b);
}
static __device__ __forceinline__ float bf2f(short s) {
    union { uint32_t u; float f; } v; v.u = ((uint32_t)(uint16_t)s) << 16; return v.f;
}
static __device__ __forceinline__ bf16x8 pack8(float4 lo, float4 hi) {
    bf16x8 r;
    r[0] = f2bf(lo.x); r[1] = f2bf(lo.y); r[2] = f2bf(lo.z); r[3] = f2bf(lo.w);
    r[4] = f2bf(hi.x); r[5] = f2bf(hi.y); r[6] = f2bf(hi.z); r[7] = f2bf(hi.w);
    return r;
}

// R16 (best, 25.6 us) with a TWO-GENERATION grid (CHUNK 512->256, 1024 blocks).
// Mechanism: gen-2 blocks' weight-gather prologue overlaps gen-1 compute, and
// gen-2 compute hides gen-1's final store drain. Weights are L2-hot for gen-2.
// Everything else identical: weights-in-VGPR, swapped MFMA, 1-tile rotating
// X prefetch, HT/OT LDS staging, full-line nt-stores, XCD sibling swizzle.
__global__ __launch_bounds__(NTM, 2)
void fused_all(const float* __restrict__ state, const float* __restrict__ action,
               const float* __restrict__ W1, const float* __restrict__ b1,
               const float* __restrict__ W2, const float* __restrict__ b2,
               const float* __restrict__ rW1, const float* __restrict__ rb1,
               const float* __restrict__ rW2, const float* __restrict__ rb2,
               float* __restrict__ outS, float* __restrict__ outR)
{
    __shared__ __align__(16) short HT[4][16][68];    //  8704 B per-wave H transpose
    __shared__ __align__(16) float OT[4][16][72];    // 18432 B per-wave output staging

    // ---- XCD sibling swizzle (bijective over 1024 blocks) ----
    // chunk = xcd + 8*chi (chi in [0,8) from high bits) -> all 16 e-siblings of
    // a chunk share XCD bid&7; X rows fetched from HBM once, L2-served after.
    const int bid = blockIdx.x;
    const int xcd = bid & 7;
    const int e   = (bid >> 3) & (Esz - 1);
    const int chi = bid >> 7;                        // [0,8)
    const int c0  = (xcd + 8 * chi) * CHUNK;

    const int w = threadIdx.x >> 6, lane = threadIdx.x & 63;
    const int lr = lane & 15, lg = lane >> 4;

    // ---- Weight fragments: per-lane gather from f32, convert once ----
    // Fragment (nt,kk): lane holds W[k = kk*32 + lg*8 + t][n = nt*16 + lr], t=0..7.
    bf16x8 w1r[4][3], rw1r[2][3], w2r[4][2];
    {
        const float* base = W1 + (size_t)e * Isz * HSz;
        #pragma unroll
        for (int nt = 0; nt < 4; ++nt)
            #pragma unroll
            for (int kk = 0; kk < 3; ++kk) {
                const float* p = base + (kk * 32 + lg * 8) * HSz + nt * 16 + lr;
                bf16x8 r;
                #pragma unroll
                for (int t = 0; t < 8; ++t) r[t] = f2bf(p[t * HSz]);
                w1r[nt][kk] = r;
            }
    }
    {
        const float* base = rW1 + (size_t)e * Isz * HRz;
        #pragma unroll
        for (int nt = 0; nt < 2; ++nt)
            #pragma unroll
            for (int kk = 0; kk < 3; ++kk) {
                const float* p = base + (kk * 32 + lg * 8) * HRz + nt * 16 + lr;
                bf16x8 r;
                #pragma unroll
                for (int t = 0; t < 8; ++t) r[t] = f2bf(p[t * HRz]);
                rw1r[nt][kk] = r;
            }
    }
    {
        const float* base = W2 + (size_t)e * HSz * Ssz;
        #pragma unroll
        for (int nt = 0; nt < 4; ++nt)
            #pragma unroll
            for (int kk = 0; kk < 2; ++kk) {
                const float* p = base + (kk * 32 + lg * 8) * Ssz + nt * 16 + lr;
                bf16x8 r;
                #pragma unroll
                for (int t = 0; t < 8; ++t) r[t] = f2bf(p[t * Ssz]);
                w2r[nt][kk] = r;
            }
    }

    // ---- Biases packed bf16 (lane's D slots: n = nt*16 + lg*4 + j) ----
    short4v b1p[4], b2p[4], rb1p[2], rw2p[2];
    #pragma unroll
    for (int nt = 0; nt < 4; ++nt) {
        float4 v1 = *(const float4*)&b1[e * HSz + nt * 16 + lg * 4];
        float4 v2 = *(const float4*)&b2[e * Ssz + nt * 16 + lg * 4];
        b1p[nt] = (short4v){ f2bf(v1.x), f2bf(v1.y), f2bf(v1.z), f2bf(v1.w) };
        b2p[nt] = (short4v){ f2bf(v2.x), f2bf(v2.y), f2bf(v2.z), f2bf(v2.w) };
    }
    #pragma unroll
    for (int nt = 0; nt < 2; ++nt) {
        float4 v1 = *(const float4*)&rb1[e * HRz + nt * 16 + lg * 4];
        float4 v2 = *(const float4*)&rW2[e * HRz + nt * 16 + lg * 4];
        rb1p[nt] = (short4v){ f2bf(v1.x), f2bf(v1.y), f2bf(v1.z), f2bf(v1.w) };
        rw2p[nt] = (short4v){ f2bf(v2.x), f2bf(v2.y), f2bf(v2.z), f2bf(v2.w) };
    }
    const float rb2s = rb2[e];

    // ---- X pipeline: f32 loads (prefetched) -> cvt_pk -> bf16 fragments ----
    const int row0 = c0 + w * 16 + lr;               // this lane's base batch row (m = lr)
    const float* sbase = state  + (size_t)row0 * Ssz + lg * 8;
    const float* abase = action + (size_t)row0 * Asz + lg * 8;

    float4 xs0 = *(const float4*)(sbase);
    float4 xs1 = *(const float4*)(sbase + 4);
    float4 xs2 = *(const float4*)(sbase + 32);
    float4 xs3 = *(const float4*)(sbase + 36);
    float4 xa0 = *(const float4*)(abase);
    float4 xa1 = *(const float4*)(abase + 4);
    bf16x8 a0 = pack8(xs0, xs1);
    bf16x8 a1 = pack8(xs2, xs3);
    bf16x8 a2 = pack8(xa0, xa1);

    #pragma unroll 1
    for (int t = 0; t < NTILE; ++t) {
        // Prefetch next tile's f32 rows (wraps on last iter; L2-hit, discarded)
        const int tn = (t + 1) & (NTILE - 1);
        const float* sp = sbase + (size_t)tn * 64 * Ssz;
        const float* ap = abase + (size_t)tn * 64 * Asz;
        float4 ns0 = *(const float4*)(sp);
        float4 ns1 = *(const float4*)(sp + 4);
        float4 ns2 = *(const float4*)(sp + 32);
        float4 ns3 = *(const float4*)(sp + 36);
        float4 na0 = *(const float4*)(ap);
        float4 na1 = *(const float4*)(ap + 4);

        // ---- Layer 1 (state): acc initialized with bias (free add) ----
        f32x4 accS[4];
        #pragma unroll
        for (int nt = 0; nt < 4; ++nt) {
            f32x4 acc = (f32x4){ bf2f(b1p[nt][0]), bf2f(b1p[nt][1]),
                                 bf2f(b1p[nt][2]), bf2f(b1p[nt][3]) };
            acc = __builtin_amdgcn_mfma_f32_16x16x32_bf16(w1r[nt][0], a0, acc, 0, 0, 0);
            acc = __builtin_amdgcn_mfma_f32_16x16x32_bf16(w1r[nt][1], a1, acc, 0, 0, 0);
            acc = __builtin_amdgcn_mfma_f32_16x16x32_bf16(w1r[nt][2], a2, acc, 0, 0, 0);
            accS[nt] = acc;
        }
        // ---- Layer 1 (reward) ----
        f32x4 accR[2];
        #pragma unroll
        for (int nt = 0; nt < 2; ++nt) {
            f32x4 acc = (f32x4){ bf2f(rb1p[nt][0]), bf2f(rb1p[nt][1]),
                                 bf2f(rb1p[nt][2]), bf2f(rb1p[nt][3]) };
            acc = __builtin_amdgcn_mfma_f32_16x16x32_bf16(rw1r[nt][0], a0, acc, 0, 0, 0);
            acc = __builtin_amdgcn_mfma_f32_16x16x32_bf16(rw1r[nt][1], a1, acc, 0, 0, 0);
            acc = __builtin_amdgcn_mfma_f32_16x16x32_bf16(rw1r[nt][2], a2, acc, 0, 0, 0);
            accR[nt] = acc;
        }

        // ---- H = relu(accS) -> HT (lane holds 4 consecutive h of row lr) ----
        #pragma unroll
        for (int nt = 0; nt < 4; ++nt) {
            short4v p = { f2bf(fmaxf(accS[nt][0], 0.f)),
                          f2bf(fmaxf(accS[nt][1], 0.f)),
                          f2bf(fmaxf(accS[nt][2], 0.f)),
                          f2bf(fmaxf(accS[nt][3], 0.f)) };
            *(short4v*)&HT[w][lr][nt * 16 + lg * 4] = p;
        }

        // ---- Reward layer 2 in registers ----
        float rp = 0.f;
        #pragma unroll
        for (int nt = 0; nt < 2; ++nt) {
            rp += fmaxf(accR[nt][0], 0.f) * bf2f(rw2p[nt][0]);
            rp += fmaxf(accR[nt][1], 0.f) * bf2f(rw2p[nt][1]);
            rp += fmaxf(accR[nt][2], 0.f) * bf2f(rw2p[nt][2]);
            rp += fmaxf(accR[nt][3], 0.f) * bf2f(rw2p[nt][3]);
        }
        rp += __shfl_xor(rp, 16);
        rp += __shfl_xor(rp, 32);
        if (lane < 16)
            __builtin_nontemporal_store(fminf(fmaxf(rp + rb2s, -100.f), 200.f),
                                        &outR[(size_t)e * Bsz + row0 + t * 64]);

        // ---- Layer 2 (state): H frags via b128; results -> OT (wave-private) ----
        bf16x8 h0 = *(const bf16x8*)&HT[w][lr][lg * 8];
        bf16x8 h1 = *(const bf16x8*)&HT[w][lr][32 + lg * 8];
        #pragma unroll
        for (int nt = 0; nt < 4; ++nt) {
            f32x4 acc = (f32x4){ bf2f(b2p[nt][0]), bf2f(b2p[nt][1]),
                                 bf2f(b2p[nt][2]), bf2f(b2p[nt][3]) };
            acc = __builtin_amdgcn_mfma_f32_16x16x32_bf16(w2r[nt][0], h0, acc, 0, 0, 0);
            acc = __builtin_amdgcn_mfma_f32_16x16x32_bf16(w2r[nt][1], h1, acc, 0, 0, 0);
            *(f32x4*)&OT[w][lr][nt * 16 + lg * 4] = acc;
        }
        // ---- Full-line coalesced stores: wave's 4 KB region as 4 x 1KB nt ----
        {
            const size_t obase = ((size_t)e * Bsz + c0 + t * 64 + w * 16) * Ssz;
            #pragma unroll
            for (int q = 0; q < 4; ++q) {
                f32x4 v = *(const f32x4*)&OT[w][4 * q + (lane >> 4)][(lane & 15) * 4];
                __builtin_nontemporal_store(v, (f32x4*)&outS[obase + q * 256 + lane * 4]);
            }
        }

        // ---- Convert prefetched f32 -> current fragments (vmcnt wait lands here) ----
        a0 = pack8(ns0, ns1);
        a1 = pack8(ns2, ns3);
        a2 = pack8(na0, na1);
    }
}

extern "C" void kernel_launch(void* const* d_in, const int* in_sizes, int n_in,
                              void* d_out, int out_size, void* d_ws, size_t ws_size,
                              hipStream_t stream) {
    const float* state  = (const float*)d_in[0];
    const float* action = (const float*)d_in[1];
    const float* W1  = (const float*)d_in[2];
    const float* b1  = (const float*)d_in[3];
    const float* W2  = (const float*)d_in[4];
    const float* b2  = (const float*)d_in[5];
    const float* rW1 = (const float*)d_in[6];
    const float* rb1 = (const float*)d_in[7];
    const float* rW2 = (const float*)d_in[8];
    const float* rb2 = (const float*)d_in[9];

    float* outS = (float*)d_out;                      // [E, B, S]
    float* outR = outS + (size_t)Esz * Bsz * Ssz;     // [E, B, 1]

    fused_all<<<Esz * (Bsz / CHUNK), NTM, 0, stream>>>(   // 1024 blocks, 2 generations
        state, action, W1, b1, W2, b2, rW1, rb1, rW2, rb2, outS, outR);
}

// Round 21
// 23.785 us; speedup vs baseline: 3.0776x; 1.2674x over previous
//
#include <hip/hip_runtime.h>
#include <hip/hip_bf16.h>
#include <cstdint>
#include <cstddef>

// Problem constants
#define Bsz 16384
#define Esz 16
#define Ssz 64
#define Asz 32
#define Isz 96   // S + A
#define HSz 64
#define HRz 32

#define NTM 256       // 4 waves
#define CHUNK 512     // batch rows per block
#define NTILE 8       // CHUNK / (4 waves * 16 rows)
#define NFRAG 26      // 12 W1 + 6 rW1 + 8 W2 fragments

typedef __attribute__((ext_vector_type(8))) short bf16x8;
typedef __attribute__((ext_vector_type(4))) short short4v;
typedef __attribute__((ext_vector_type(4))) float f32x4;

static __device__ __forceinline__ short f2bf(float f) {
    __hip_bfloat16 b = __float2bfloat16(f);   // pairs into v_cvt_pk_bf16_f32
    return *reinterpret_cast<short*>(&b);
}
static __device__ __forceinline__ float bf2f(short s) {
    union { uint32_t u; float f; } v; v.u = ((uint32_t)(uint16_t)s) << 16; return v.f;
}
static __device__ __forceinline__ bf16x8 pack8(float4 lo, float4 hi) {
    bf16x8 r;
    r[0] = f2bf(lo.x); r[1] = f2bf(lo.y); r[2] = f2bf(lo.z); r[3] = f2bf(lo.w);
    r[4] = f2bf(hi.x); r[5] = f2bf(hi.y); r[6] = f2bf(hi.z); r[7] = f2bf(hi.w);
    return r;
}

// R16 (best, 25.6 us) + COOPERATIVE FRAGMENT GATHER.
// The 26x64 weight-fragment units are gathered ONCE per block (not once per
// wave): 256 threads split the 1664 units (8 scalar loads + 1 ds_write_b128
// each), barrier, then every wave reads its 26 fragments as ds_read_b128.
// Cuts per-CU prologue VMEM instructions 4x (1664 -> 416). First X-tile loads
// hoisted above the gather so HBM latency overlaps it. Steady-state loop,
// swapped MFMA, XCD swizzle, HT/OT staging, full-line nt-stores: identical.
__global__ __launch_bounds__(NTM, 2)
void fused_all(const float* __restrict__ state, const float* __restrict__ action,
               const float* __restrict__ W1, const float* __restrict__ b1,
               const float* __restrict__ W2, const float* __restrict__ b2,
               const float* __restrict__ rW1, const float* __restrict__ rb1,
               const float* __restrict__ rW2, const float* __restrict__ rb2,
               float* __restrict__ outS, float* __restrict__ outR)
{
    __shared__ __align__(16) short HT[4][16][68];      //  8704 B per-wave H transpose
    __shared__ __align__(16) float OT[4][16][72];      // 18432 B per-wave output staging
    __shared__ __align__(16) short WLf[NFRAG * 64 * 8];// 26624 B fragment-ordered weights
    // total 53760 B -> 2 blocks/CU (107.5 KB < 160 KB)

    // ---- XCD-aware sibling swizzle (bijective over 512 blocks) ----
    const int bid = blockIdx.x;
    const int xcd = bid & 7;
    const int rem = bid >> 3;
    const int e   = rem & (Esz - 1);
    const int c0  = (xcd + 8 * (rem >> 4)) * CHUNK;

    const int tid = threadIdx.x;
    const int w = tid >> 6, lane = tid & 63;
    const int lr = lane & 15, lg = lane >> 4;

    // ---- First X tile loads issued EARLY (latency overlaps the gather) ----
    const int row0 = c0 + w * 16 + lr;               // this lane's base batch row (m = lr)
    const float* sbase = state  + (size_t)row0 * Ssz + lg * 8;
    const float* abase = action + (size_t)row0 * Asz + lg * 8;
    float4 xs0 = *(const float4*)(sbase);
    float4 xs1 = *(const float4*)(sbase + 4);
    float4 xs2 = *(const float4*)(sbase + 32);
    float4 xs3 = *(const float4*)(sbase + 36);
    float4 xa0 = *(const float4*)(abase);
    float4 xa1 = *(const float4*)(abase + 4);

    // ---- Cooperative gather: 1664 fragment units split across 256 threads ----
    // Unit (f, l): 8 f32 loads in fragment order -> bf16x8 -> WLf[f*64 + l].
    // Fragment f: [0,12) W1 (f = nt*3+kk), [12,18) rW1, [18,26) W2.
    // Per-unit layout: lane l holds W[k = kk*32 + (l>>4)*8 + t][n = nt*16 + (l&15)].
    for (int u = tid; u < NFRAG * 64; u += NTM) {
        const int f = u >> 6, l = u & 63;
        const int llr = l & 15, llg = l >> 4;
        const float* p;
        int stride;
        if (f < 12) {
            int nt = f / 3, kk = f - nt * 3;
            p = W1 + (size_t)e * Isz * HSz + (kk * 32 + llg * 8) * HSz + nt * 16 + llr;
            stride = HSz;
        } else if (f < 18) {
            int f1 = f - 12;
            int nt = f1 / 3, kk = f1 - nt * 3;
            p = rW1 + (size_t)e * Isz * HRz + (kk * 32 + llg * 8) * HRz + nt * 16 + llr;
            stride = HRz;
        } else {
            int f1 = f - 18;
            int nt = f1 >> 1, kk = f1 & 1;
            p = W2 + (size_t)e * HSz * Ssz + (kk * 32 + llg * 8) * Ssz + nt * 16 + llr;
            stride = Ssz;
        }
        bf16x8 r;
        #pragma unroll
        for (int t = 0; t < 8; ++t) r[t] = f2bf(p[t * stride]);
        *(bf16x8*)&WLf[u * 8] = r;
    }

    // ---- Biases packed bf16 (lane's D slots: n = nt*16 + lg*4 + j) ----
    short4v b1p[4], b2p[4], rb1p[2], rw2p[2];
    #pragma unroll
    for (int nt = 0; nt < 4; ++nt) {
        float4 v1 = *(const float4*)&b1[e * HSz + nt * 16 + lg * 4];
        float4 v2 = *(const float4*)&b2[e * Ssz + nt * 16 + lg * 4];
        b1p[nt] = (short4v){ f2bf(v1.x), f2bf(v1.y), f2bf(v1.z), f2bf(v1.w) };
        b2p[nt] = (short4v){ f2bf(v2.x), f2bf(v2.y), f2bf(v2.z), f2bf(v2.w) };
    }
    #pragma unroll
    for (int nt = 0; nt < 2; ++nt) {
        float4 v1 = *(const float4*)&rb1[e * HRz + nt * 16 + lg * 4];
        float4 v2 = *(const float4*)&rW2[e * HRz + nt * 16 + lg * 4];
        rb1p[nt] = (short4v){ f2bf(v1.x), f2bf(v1.y), f2bf(v1.z), f2bf(v1.w) };
        rw2p[nt] = (short4v){ f2bf(v2.x), f2bf(v2.y), f2bf(v2.z), f2bf(v2.w) };
    }
    const float rb2s = rb2[e];

    __syncthreads();   // WLf staged

    // ---- Each wave pulls its fragments: 26 ds_read_b128 ----
    bf16x8 w1r[4][3], rw1r[2][3], w2r[4][2];
    #pragma unroll
    for (int nt = 0; nt < 4; ++nt)
        #pragma unroll
        for (int kk = 0; kk < 3; ++kk)
            w1r[nt][kk] = *(const bf16x8*)&WLf[((nt * 3 + kk) * 64 + lane) * 8];
    #pragma unroll
    for (int nt = 0; nt < 2; ++nt)
        #pragma unroll
        for (int kk = 0; kk < 3; ++kk)
            rw1r[nt][kk] = *(const bf16x8*)&WLf[((12 + nt * 3 + kk) * 64 + lane) * 8];
    #pragma unroll
    for (int nt = 0; nt < 4; ++nt)
        #pragma unroll
        for (int kk = 0; kk < 2; ++kk)
            w2r[nt][kk] = *(const bf16x8*)&WLf[((18 + nt * 2 + kk) * 64 + lane) * 8];

    // ---- Pack first A-fragments (loads issued before gather) ----
    bf16x8 a0 = pack8(xs0, xs1);
    bf16x8 a1 = pack8(xs2, xs3);
    bf16x8 a2 = pack8(xa0, xa1);

    #pragma unroll 1
    for (int t = 0; t < NTILE; ++t) {
        // Prefetch next tile's f32 rows (wraps on last iter; L2-hit, discarded)
        const int tn = (t + 1) & (NTILE - 1);
        const float* sp = sbase + (size_t)tn * 64 * Ssz;
        const float* ap = abase + (size_t)tn * 64 * Asz;
        float4 ns0 = *(const float4*)(sp);
        float4 ns1 = *(const float4*)(sp + 4);
        float4 ns2 = *(const float4*)(sp + 32);
        float4 ns3 = *(const float4*)(sp + 36);
        float4 na0 = *(const float4*)(ap);
        float4 na1 = *(const float4*)(ap + 4);

        // ---- Layer 1 (state): acc initialized with bias (free add) ----
        f32x4 accS[4];
        #pragma unroll
        for (int nt = 0; nt < 4; ++nt) {
            f32x4 acc = (f32x4){ bf2f(b1p[nt][0]), bf2f(b1p[nt][1]),
                                 bf2f(b1p[nt][2]), bf2f(b1p[nt][3]) };
            acc = __builtin_amdgcn_mfma_f32_16x16x32_bf16(w1r[nt][0], a0, acc, 0, 0, 0);
            acc = __builtin_amdgcn_mfma_f32_16x16x32_bf16(w1r[nt][1], a1, acc, 0, 0, 0);
            acc = __builtin_amdgcn_mfma_f32_16x16x32_bf16(w1r[nt][2], a2, acc, 0, 0, 0);
            accS[nt] = acc;
        }
        // ---- Layer 1 (reward) ----
        f32x4 accR[2];
        #pragma unroll
        for (int nt = 0; nt < 2; ++nt) {
            f32x4 acc = (f32x4){ bf2f(rb1p[nt][0]), bf2f(rb1p[nt][1]),
                                 bf2f(rb1p[nt][2]), bf2f(rb1p[nt][3]) };
            acc = __builtin_amdgcn_mfma_f32_16x16x32_bf16(rw1r[nt][0], a0, acc, 0, 0, 0);
            acc = __builtin_amdgcn_mfma_f32_16x16x32_bf16(rw1r[nt][1], a1, acc, 0, 0, 0);
            acc = __builtin_amdgcn_mfma_f32_16x16x32_bf16(rw1r[nt][2], a2, acc, 0, 0, 0);
            accR[nt] = acc;
        }

        // ---- H = relu(accS) -> HT (lane holds 4 consecutive h of row lr) ----
        #pragma unroll
        for (int nt = 0; nt < 4; ++nt) {
            short4v p = { f2bf(fmaxf(accS[nt][0], 0.f)),
                          f2bf(fmaxf(accS[nt][1], 0.f)),
                          f2bf(fmaxf(accS[nt][2], 0.f)),
                          f2bf(fmaxf(accS[nt][3], 0.f)) };
            *(short4v*)&HT[w][lr][nt * 16 + lg * 4] = p;
        }

        // ---- Reward layer 2 in registers ----
        float rp = 0.f;
        #pragma unroll
        for (int nt = 0; nt < 2; ++nt) {
            rp += fmaxf(accR[nt][0], 0.f) * bf2f(rw2p[nt][0]);
            rp += fmaxf(accR[nt][1], 0.f) * bf2f(rw2p[nt][1]);
            rp += fmaxf(accR[nt][2], 0.f) * bf2f(rw2p[nt][2]);
            rp += fmaxf(accR[nt][3], 0.f) * bf2f(rw2p[nt][3]);
        }
        rp += __shfl_xor(rp, 16);
        rp += __shfl_xor(rp, 32);
        if (lane < 16)
            __builtin_nontemporal_store(fminf(fmaxf(rp + rb2s, -100.f), 200.f),
                                        &outR[(size_t)e * Bsz + row0 + t * 64]);

        // ---- Layer 2 (state): H frags via b128; results -> OT (wave-private) ----
        bf16x8 h0 = *(const bf16x8*)&HT[w][lr][lg * 8];
        bf16x8 h1 = *(const bf16x8*)&HT[w][lr][32 + lg * 8];
        #pragma unroll
        for (int nt = 0; nt < 4; ++nt) {
            f32x4 acc = (f32x4){ bf2f(b2p[nt][0]), bf2f(b2p[nt][1]),
                                 bf2f(b2p[nt][2]), bf2f(b2p[nt][3]) };
            acc = __builtin_amdgcn_mfma_f32_16x16x32_bf16(w2r[nt][0], h0, acc, 0, 0, 0);
            acc = __builtin_amdgcn_mfma_f32_16x16x32_bf16(w2r[nt][1], h1, acc, 0, 0, 0);
            *(f32x4*)&OT[w][lr][nt * 16 + lg * 4] = acc;
        }
        // ---- Full-line coalesced stores: wave's 4 KB region as 4 x 1KB nt ----
        {
            const size_t obase = ((size_t)e * Bsz + c0 + t * 64 + w * 16) * Ssz;
            #pragma unroll
            for (int q = 0; q < 4; ++q) {
                f32x4 v = *(const f32x4*)&OT[w][4 * q + (lane >> 4)][(lane & 15) * 4];
                __builtin_nontemporal_store(v, (f32x4*)&outS[obase + q * 256 + lane * 4]);
            }
        }

        // ---- Convert prefetched f32 -> current fragments (vmcnt wait lands here) ----
        a0 = pack8(ns0, ns1);
        a1 = pack8(ns2, ns3);
        a2 = pack8(na0, na1);
    }
}

extern "C" void kernel_launch(void* const* d_in, const int* in_sizes, int n_in,
                              void* d_out, int out_size, void* d_ws, size_t ws_size,
                              hipStream_t stream) {
    const float* state  = (const float*)d_in[0];
    const float* action = (const float*)d_in[1];
    const float* W1  = (const float*)d_in[2];
    const float* b1  = (const float*)d_in[3];
    const float* W2  = (const float*)d_in[4];
    const float* b2  = (const float*)d_in[5];
    const float* rW1 = (const float*)d_in[6];
    const float* rb1 = (const float*)d_in[7];
    const float* rW2 = (const float*)d_in[8];
    const float* rb2 = (const float*)d_in[9];

    float* outS = (float*)d_out;                      // [E, B, S]
    float* outR = outS + (size_t)Esz * Bsz * Ssz;     // [E, B, 1]

    fused_all<<<Esz * (Bsz / CHUNK), NTM, 0, stream>>>(   // 512 blocks, 1 generation
        state, action, W1, b1, W2, b2, rW1, rb1, rW2, rb2, outS, outR);
}